// Round 4
// baseline (265.316 us; speedup 1.0000x reference)
//
#include <hip/hip_runtime.h>
#include <hip/hip_bf16.h>

// ---------------------------------------------------------------------------
// Attention_58248346469030:  out = softmax((x@Wq)(x@Wk)^T * sc) @ (x@Wv) @ Wout + b
// B=4, S=2048, DIM=1024, INNER=1024 (full-dim attention, no head split).
//
// Pipeline (fp16/bf16 MFMA, fp32 accumulate):
//   prep:  x -> fp16;  W_qkv -> fp16 transposed [n][k] (q pre-scaled by 0.125);
//          W_out -> fp16 transposed.
//   1) qkv  = x @ W_qkv       (q/k fp16 -> qkv buf; v bf16 -> VT transposed)
//   2) P    = exp(q @ k^T)    (fp16 MFMA, bf16 out, no max-subtract: |dots|<~25)
//   3) invl = 1 / rowsum(P)
//   4) attn = (P @ V) * invl  (bf16 MFMA, fp16 out)
//   5) out  = attn @ W_out + b
//
// GEMM core: 256x256 tile, BK=64, 512 thr (8 waves 2Mx4N, wave-tile 128x64 ->
// LDS/MFMA ratio 0.62), 128KB dbuf LDS, T2 XOR-swizzle via pre-swizzled global
// source, counted s_waitcnt vmcnt(8) pipeline (never drains fresh prefetch),
// 4 quadrant phases with raw barriers + setprio (T3/T4/T5).
// ---------------------------------------------------------------------------

typedef short    s16x8 __attribute__((ext_vector_type(8)));
typedef short    s16x4 __attribute__((ext_vector_type(4)));
typedef float    fx4   __attribute__((ext_vector_type(4)));
typedef _Float16 h16x8 __attribute__((ext_vector_type(8)));

__device__ __forceinline__ short f2bs(float f) {
  __hip_bfloat16 h = __float2bfloat16(f);
  short s; __builtin_memcpy(&s, &h, 2); return s;
}
__device__ __forceinline__ short f2hs(float f) {
  _Float16 h = (_Float16)f;
  short s; __builtin_memcpy(&s, &h, 2); return s;
}
__device__ __forceinline__ float b2f(short s) {
  unsigned u = ((unsigned)(unsigned short)s) << 16;
  float f; __builtin_memcpy(&f, &u, 4); return f;
}

__device__ __forceinline__ void gload16(const void* g, void* l) {
  __builtin_amdgcn_global_load_lds(
      (const __attribute__((address_space(1))) void*)g,
      (__attribute__((address_space(3))) void*)l, 16, 0, 0);
}

// ---------------- prep kernels ----------------

__global__ void cvt_f32_f16(const float* __restrict__ in, short* __restrict__ out, int n4) {
  int i = blockIdx.x * blockDim.x + threadIdx.x;
  if (i < n4) {
    float4 v = reinterpret_cast<const float4*>(in)[i];
    s16x4 o;
    o.x = f2hs(v.x); o.y = f2hs(v.y); o.z = f2hs(v.z); o.w = f2hs(v.w);
    reinterpret_cast<s16x4*>(out)[i] = o;
  }
}

__global__ void transpose_w(const float* __restrict__ W, int K, int N,
                            short* __restrict__ WT, float qscale, int scaleN) {
  __shared__ float tile[32][33];
  int k0 = blockIdx.y * 32, n0 = blockIdx.x * 32;
  int r = threadIdx.x >> 5, c = threadIdx.x & 31;
  for (int rr = r; rr < 32; rr += 8)
    tile[rr][c] = W[(size_t)(k0 + rr) * N + n0 + c];
  __syncthreads();
  for (int rr = r; rr < 32; rr += 8) {
    int n = n0 + rr;
    float s = (n < scaleN) ? qscale : 1.0f;
    WT[(size_t)n * K + k0 + c] = f2hs(tile[c][rr] * s);
  }
}

// invl[row] = 1 / sum_t P[row][t]
__global__ void row_sums(const short* __restrict__ P, float* __restrict__ invl) {
  int wid = threadIdx.x >> 6, lane = threadIdx.x & 63;
  int row = blockIdx.x * 4 + wid;
  const short* p = P + (size_t)row * 2048;
  float s = 0.f;
#pragma unroll
  for (int seg = 0; seg < 4; ++seg) {
    s16x8 v = *reinterpret_cast<const s16x8*>(p + seg * 512 + lane * 8);
#pragma unroll
    for (int j = 0; j < 8; ++j) s += b2f(v[j]);
  }
#pragma unroll
  for (int off = 32; off; off >>= 1) s += __shfl_xor(s, off);
  if (lane == 0) invl[row] = 1.0f / s;
}

// ---------------- 256x256 8-wave counted-vmcnt GEMM ----------------
// C[M][N] = A[M][K] @ B'[N][K]^T, 16-bit operands, k-contiguous rows.
// EPI: 0 = qkv write (q/k fp16 -> Cv; v bf16 -> Cv2=VT[b][d][t] transposed)
//      1 = exp -> bf16     2 = *aux[row] -> fp16     3 = +aux[col] -> fp32
template<int EPI, int DT>
__global__ __launch_bounds__(512, 2)
void gemm256(const short* __restrict__ A, int lda, long long bsA,
             const short* __restrict__ B, int ldb, long long bsB,
             void* __restrict__ Cv, int ldc, long long bsC,
             int K, const float* __restrict__ aux, long long bsAux,
             short* __restrict__ Cv2) {
  __shared__ __align__(16) short As[2][256 * 64];   // 2 x 32KB
  __shared__ __align__(16) short Bs[2][256 * 64];   // 2 x 32KB

  const int t = threadIdx.x;
  const int z = blockIdx.z;
  A += (size_t)z * bsA;
  B += (size_t)z * bsB;

  const int brow = blockIdx.y * 256;
  const int bcol = blockIdx.x * 256;

  const int lane = t & 63;
  const int wid  = t >> 6;
  const int wm = wid >> 2;               // 0/1  -> rows wm*128..+127
  const int wn = wid & 3;                // 0..3 -> cols wn*64..+63
  const int fr = lane & 15;
  const int fg = lane >> 4;

  // staging: 32 chunks of 1KB (8 rows x 64 cols) per operand; wave stages
  // chunks wid*4..wid*4+3. LDS dest linear; global source pre-swizzled
  // (T2: LDS (row,col) holds global (row, col ^ ((row&7)<<3))).
  const int l8 = lane >> 3, l7 = lane & 7;
  const int scol = (l7 ^ l8) * 8;
  const short *Ag[4], *Bg[4];
#pragma unroll
  for (int j = 0; j < 4; ++j) {
    const int ch = wid * 4 + j;
    Ag[j] = A + (size_t)(brow + ch * 8 + l8) * lda + scol;
    Bg[j] = B + (size_t)(bcol + ch * 8 + l8) * ldb + scol;
  }
  const int chBase = wid * 4 * 512;      // + j*512 (shorts)

  // frag-read bases (swizzled column offsets); row&7 == fr&7 here.
  const int f7  = fr & 7;
  const int co0 = (fg ^ f7) * 8;         // kk = 0
  const int co1 = co0 ^ 32;              // kk = 32

  fx4 acc[8][4] = {};
  const int NT = K >> 6;

  auto MM = [&](s16x8 av, s16x8 bv, fx4 c) -> fx4 {
    if constexpr (DT == 0)
      return __builtin_amdgcn_mfma_f32_16x16x32_f16(
          __builtin_bit_cast(h16x8, av), __builtin_bit_cast(h16x8, bv), c, 0, 0, 0);
    else
      return __builtin_amdgcn_mfma_f32_16x16x32_bf16(av, bv, c, 0, 0, 0);
  };

  // prologue: stage tile 0 into buf 0
#pragma unroll
  for (int j = 0; j < 4; ++j) {
    gload16(Ag[j], &As[0][chBase + j * 512]);
    gload16(Bg[j], &Bs[0][chBase + j * 512]);
  }

  for (int tt = 0; tt < NT; ++tt) {
    const short* Ab = As[tt & 1];
    const short* Bb = Bs[tt & 1];

    __builtin_amdgcn_s_barrier();        // B1: buf p^1 reads (tile tt-1) done
    __builtin_amdgcn_sched_barrier(0);
    if (tt + 1 < NT) {                   // stage tile tt+1 into buf p^1
      const int kt = (tt + 1) << 6;
      short* Ad = &As[(tt + 1) & 1][0];
      short* Bd = &Bs[(tt + 1) & 1][0];
#pragma unroll
      for (int j = 0; j < 4; ++j) {
        gload16(Ag[j] + kt, Ad + chBase + j * 512);
        gload16(Bg[j] + kt, Bd + chBase + j * 512);
      }
      asm volatile("s_waitcnt vmcnt(8)" ::: "memory");   // tile tt landed (own)
    } else {
      asm volatile("s_waitcnt vmcnt(0)" ::: "memory");
    }
    __builtin_amdgcn_s_barrier();        // B2: tile tt landed (all waves)
    __builtin_amdgcn_sched_barrier(0);

    const short* Arow = Ab + (wm * 128 + fr) * 64;
    const short* Brow = Bb + (wn * 64 + fr) * 64;
    s16x8 a[4][2], b[4][2];

    // ---- Q1: read a(m0-3) + b(n0-1); MFMA m0-3 x n0-1 ----
#pragma unroll
    for (int m = 0; m < 4; ++m) {
      a[m][0] = *reinterpret_cast<const s16x8*>(Arow + m * 1024 + co0);
      a[m][1] = *reinterpret_cast<const s16x8*>(Arow + m * 1024 + co1);
    }
#pragma unroll
    for (int n = 0; n < 2; ++n) {
      b[n][0] = *reinterpret_cast<const s16x8*>(Brow + n * 1024 + co0);
      b[n][1] = *reinterpret_cast<const s16x8*>(Brow + n * 1024 + co1);
    }
    asm volatile("s_waitcnt lgkmcnt(0)" ::: "memory");
    __builtin_amdgcn_sched_barrier(0);
    __builtin_amdgcn_s_setprio(1);
#pragma unroll
    for (int m = 0; m < 4; ++m)
#pragma unroll
      for (int n = 0; n < 2; ++n)
#pragma unroll
        for (int kk = 0; kk < 2; ++kk)
          acc[m][n] = MM(a[m][kk], b[n][kk], acc[m][n]);
    __builtin_amdgcn_s_setprio(0);
    __builtin_amdgcn_s_barrier();

    // ---- Q2: read b(n2-3); MFMA m0-3 x n2-3 ----
#pragma unroll
    for (int n = 2; n < 4; ++n) {
      b[n][0] = *reinterpret_cast<const s16x8*>(Brow + n * 1024 + co0);
      b[n][1] = *reinterpret_cast<const s16x8*>(Brow + n * 1024 + co1);
    }
    asm volatile("s_waitcnt lgkmcnt(0)" ::: "memory");
    __builtin_amdgcn_sched_barrier(0);
    __builtin_amdgcn_s_setprio(1);
#pragma unroll
    for (int m = 0; m < 4; ++m)
#pragma unroll
      for (int n = 2; n < 4; ++n)
#pragma unroll
        for (int kk = 0; kk < 2; ++kk)
          acc[m][n] = MM(a[m][kk], b[n][kk], acc[m][n]);
    __builtin_amdgcn_s_setprio(0);
    __builtin_amdgcn_s_barrier();

    // ---- Q3: read a(m4-7) (overwrite); MFMA m4-7 x n0-1 ----
#pragma unroll
    for (int m = 0; m < 4; ++m) {
      a[m][0] = *reinterpret_cast<const s16x8*>(Arow + (m + 4) * 1024 + co0);
      a[m][1] = *reinterpret_cast<const s16x8*>(Arow + (m + 4) * 1024 + co1);
    }
    asm volatile("s_waitcnt lgkmcnt(0)" ::: "memory");
    __builtin_amdgcn_sched_barrier(0);
    __builtin_amdgcn_s_setprio(1);
#pragma unroll
    for (int m = 0; m < 4; ++m)
#pragma unroll
      for (int n = 0; n < 2; ++n)
#pragma unroll
        for (int kk = 0; kk < 2; ++kk)
          acc[m + 4][n] = MM(a[m][kk], b[n][kk], acc[m + 4][n]);
    __builtin_amdgcn_s_setprio(0);
    __builtin_amdgcn_s_barrier();

    // ---- Q4: MFMA m4-7 x n2-3 (all regs held) ----
    __builtin_amdgcn_s_setprio(1);
#pragma unroll
    for (int m = 0; m < 4; ++m)
#pragma unroll
      for (int n = 2; n < 4; ++n)
#pragma unroll
        for (int kk = 0; kk < 2; ++kk)
          acc[m + 4][n] = MM(a[m][kk], b[n][kk], acc[m + 4][n]);
    __builtin_amdgcn_s_setprio(0);
  }

  // ---- epilogue: D row = fg*4 + j, col = fr (per 16x16 frag) ----
  const int row0 = brow + wm * 128 + fg * 4;
  const int col0 = bcol + wn * 64 + fr;
  const float* auxp = aux + (size_t)z * bsAux;
  if constexpr (EPI == 3) {
    float* Cf = reinterpret_cast<float*>(Cv) + (size_t)z * bsC;
#pragma unroll
    for (int m = 0; m < 8; ++m)
#pragma unroll
      for (int n = 0; n < 4; ++n) {
        const int col = col0 + n * 16;
        const float bo = auxp[col];
#pragma unroll
        for (int j = 0; j < 4; ++j)
          Cf[(size_t)(row0 + m * 16 + j) * ldc + col] = acc[m][n][j] + bo;
      }
  } else if constexpr (EPI == 0) {
    short* Cb = reinterpret_cast<short*>(Cv);
    if (bcol < 2048) {                    // q/k columns -> fp16, row-major
#pragma unroll
      for (int m = 0; m < 8; ++m)
#pragma unroll
        for (int j = 0; j < 4; ++j) {
          const int row = row0 + m * 16 + j;
#pragma unroll
          for (int n = 0; n < 4; ++n)
            Cb[(size_t)row * ldc + col0 + n * 16] = f2hs(acc[m][n][j]);
        }
    } else {                              // v columns -> bf16 into VT[b][d][t]
#pragma unroll
      for (int m = 0; m < 8; ++m)
#pragma unroll
        for (int j = 0; j < 4; ++j) {
          const int row = row0 + m * 16 + j;
          const int zb = row >> 11, s = row & 2047;
#pragma unroll
          for (int n = 0; n < 4; ++n) {
            const int d = col0 + n * 16 - 2048;
            Cv2[((size_t)(zb << 10) + d) * 2048 + s] = f2bs(acc[m][n][j]);
          }
        }
    }
  } else {
    short* Cb = reinterpret_cast<short*>(Cv) + (size_t)z * bsC;
#pragma unroll
    for (int m = 0; m < 8; ++m)
#pragma unroll
      for (int j = 0; j < 4; ++j) {
        const int row = row0 + m * 16 + j;
        float rs = 1.0f;
        if constexpr (EPI == 2) rs = auxp[row];
#pragma unroll
        for (int n = 0; n < 4; ++n) {
          float v = acc[m][n][j];
          short o;
          if constexpr (EPI == 1) o = f2bs(exp2f(v * 1.4426950408889634f));
          else                    o = f2hs(v * rs);
          Cb[(size_t)row * ldc + col0 + n * 16] = o;
        }
      }
  }
}

// ---------------- launch ----------------

extern "C" void kernel_launch(void* const* d_in, const int* in_sizes, int n_in,
                              void* d_out, int out_size, void* d_ws, size_t ws_size,
                              hipStream_t stream) {
  const float* x    = (const float*)d_in[0];   // [4,2048,1024]
  const float* Wqkv = (const float*)d_in[1];   // [1024,3072]
  const float* Wout = (const float*)d_in[2];   // [1024,1024]
  const float* bout = (const float*)d_in[3];   // [1024]
  float* out = (float*)d_out;                  // [4,2048,1024] fp32

  char* ws = (char*)d_ws;
  short* qkv   = (short*)(ws + 0);             //  50331648  q/k fp16 [8192][3072]
  short* WqkvT = (short*)(ws + 50331648);      //   6291456  fp16 [3072][1024]
  short* WoutT = (short*)(ws + 56623104);      //   2097152  fp16 [1024][1024]
  short* P     = (short*)(ws + 58720256);      //  33554432  bf16 [4][2048][2048]
  short* VT    = (short*)(ws + 92274688);      //  16777216  bf16 [4][1024][2048]
  short* xh    = (short*)(ws + 109051904);     //  16777216  fp16 x (reused as attn)
  float* invl  = (float*)(ws + 125829120);     //     32768
  if (ws_size < 125861888) return;
  short* attn = xh;

  cvt_f32_f16<<<8192, 256, 0, stream>>>(x, xh, 8388608 / 4);
  transpose_w<<<dim3(96, 32), 256, 0, stream>>>(Wqkv, 1024, 3072, WqkvT, 0.125f, 1024);
  transpose_w<<<dim3(32, 32), 256, 0, stream>>>(Wout, 1024, 1024, WoutT, 1.0f, 0);

  // qkv = x @ W_qkv   (v written transposed into VT)
  gemm256<0, 0><<<dim3(12, 32, 1), 512, 0, stream>>>(
      xh, 1024, 0, WqkvT, 1024, 0, qkv, 3072, 0, 1024, bout, 0, VT);
  // P = exp(q @ k^T)
  gemm256<1, 0><<<dim3(8, 8, 4), 512, 0, stream>>>(
      qkv, 3072, 2048LL * 3072, qkv + 1024, 3072, 2048LL * 3072,
      P, 2048, 2048LL * 2048, 1024, bout, 0, nullptr);
  row_sums<<<2048, 256, 0, stream>>>(P, invl);
  // attn = (P @ V) * invl
  gemm256<2, 1><<<dim3(4, 8, 4), 512, 0, stream>>>(
      P, 2048, 2048LL * 2048, VT, 2048, 1024LL * 2048,
      attn, 1024, 2048LL * 1024, 2048, invl, 2048, nullptr);
  // out = attn @ W_out + b
  gemm256<3, 0><<<dim3(4, 32, 1), 512, 0, stream>>>(
      attn, 1024, 0, WoutT, 1024, 0, out, 1024, 0, 1024, bout, 0, nullptr);
}

// Round 5
// 255.262 us; speedup vs baseline: 1.0394x; 1.0394x over previous
//
#include <hip/hip_runtime.h>
#include <hip/hip_bf16.h>

// ---------------------------------------------------------------------------
// Attention_58248346469030:  out = softmax((x@Wq)(x@Wk)^T * sc) @ (x@Wv) @ Wout + b
// B=4, S=2048, DIM=1024, INNER=1024 (full-dim attention, no head split).
//
// Pipeline (fp16/bf16 MFMA, fp32 accumulate):
//   prep:  x -> fp16;  W_qkv -> fp16 transposed [n][k] (q pre-scaled by 0.125);
//          W_out -> fp16 transposed.
//   1) qkv  = x @ W_qkv            (fp16 in; q/k fp16, v bf16)
//   2) P    = exp(q @ k^T)         (fp16 MFMA, bf16 out; no max-subtract)
//   3) invl = 1 / rowsum(P);  VT = transpose(v)
//   4) attn = (P @ V) * invl       (bf16 MFMA, fp16 out)
//   5) out  = attn @ W_out + b     (fp16 MFMA, fp32 out)
//
// GEMM core: R1 skeleton (128x128 tile, BK=64, 4 waves, padded LDS stride 72,
// reg-staged) + T14 cross-tile register prefetch (loads for tile t+1 issued
// before computing tile t) + T1 XCD-aware block swizzle. Grids all multiples
// of 256 (balanced) and of 8 (swizzle-safe). 36KB LDS -> 4 blocks/CU.
// ---------------------------------------------------------------------------

typedef short    s16x8 __attribute__((ext_vector_type(8)));
typedef short    s16x4 __attribute__((ext_vector_type(4)));
typedef float    fx4   __attribute__((ext_vector_type(4)));
typedef _Float16 h16x8 __attribute__((ext_vector_type(8)));

__device__ __forceinline__ short f2bs(float f) {            // f32 -> bf16 bits (RNE)
  __hip_bfloat16 h = __float2bfloat16(f);
  short s; __builtin_memcpy(&s, &h, 2); return s;
}
__device__ __forceinline__ short f2hs(float f) {            // f32 -> fp16 bits (RNE)
  _Float16 h = (_Float16)f;
  short s; __builtin_memcpy(&s, &h, 2); return s;
}
__device__ __forceinline__ float b2f(short s) {             // bf16 bits -> f32
  unsigned u = ((unsigned)(unsigned short)s) << 16;
  float f; __builtin_memcpy(&f, &u, 4); return f;
}

// ---------------- prep kernels ----------------

__global__ void cvt_f32_f16(const float* __restrict__ in, short* __restrict__ out, int n4) {
  int i = blockIdx.x * blockDim.x + threadIdx.x;
  if (i < n4) {
    float4 v = reinterpret_cast<const float4*>(in)[i];
    s16x4 o;
    o.x = f2hs(v.x); o.y = f2hs(v.y); o.z = f2hs(v.z); o.w = f2hs(v.w);
    reinterpret_cast<s16x4*>(out)[i] = o;
  }
}

// WT[n][k] = W[k][n] * (n < scaleN ? qscale : 1), fp16 out.
__global__ void transpose_w(const float* __restrict__ W, int K, int N,
                            short* __restrict__ WT, float qscale, int scaleN) {
  __shared__ float tile[32][33];
  int k0 = blockIdx.y * 32, n0 = blockIdx.x * 32;
  int r = threadIdx.x >> 5, c = threadIdx.x & 31;
  for (int rr = r; rr < 32; rr += 8)
    tile[rr][c] = W[(size_t)(k0 + rr) * N + n0 + c];
  __syncthreads();
  for (int rr = r; rr < 32; rr += 8) {
    int n = n0 + rr;
    float s = (n < scaleN) ? qscale : 1.0f;
    WT[(size_t)n * K + k0 + c] = f2hs(tile[c][rr] * s);
  }
}

// VT[b][d][t] = qkv[b][t][2048 + d]   (bf16 passthrough, coalesced both sides)
__global__ void transpose_v(const short* __restrict__ qkv, short* __restrict__ VT) {
  __shared__ short tile[32][33];
  int b = blockIdx.z;
  const short* Vin = qkv + (size_t)b * 2048 * 3072 + 2048;
  short* Vout = VT + (size_t)b * 1024 * 2048;
  int t0 = blockIdx.y * 32, d0 = blockIdx.x * 32;
  int r = threadIdx.x >> 5, c = threadIdx.x & 31;
  for (int rr = r; rr < 32; rr += 8)
    tile[rr][c] = Vin[(size_t)(t0 + rr) * 3072 + d0 + c];
  __syncthreads();
  for (int rr = r; rr < 32; rr += 8)
    Vout[(size_t)(d0 + rr) * 2048 + t0 + c] = tile[c][rr];
}

// invl[row] = 1 / sum_t P[row][t]   (one wave per row, 4 rows per block)
__global__ void row_sums(const short* __restrict__ P, float* __restrict__ invl) {
  int wid = threadIdx.x >> 6, lane = threadIdx.x & 63;
  int row = blockIdx.x * 4 + wid;
  const short* p = P + (size_t)row * 2048;
  float s = 0.f;
#pragma unroll
  for (int seg = 0; seg < 4; ++seg) {
    s16x8 v = *reinterpret_cast<const s16x8*>(p + seg * 512 + lane * 8);
#pragma unroll
    for (int j = 0; j < 8; ++j) s += b2f(v[j]);
  }
#pragma unroll
  for (int off = 32; off; off >>= 1) s += __shfl_xor(s, off);
  if (lane == 0) invl[row] = 1.0f / s;
}

// ---------------- shared GEMM skeleton (R1 + T14 prefetch + T1 swizzle) ----
// C[M][N] = A[M][K] @ B'[N][K]^T  (both operands 16-bit, k-contiguous rows)
// 128x128 tile, BK=64, 4 waves (2x2), each wave 64x64 = 4x4 16x16x32 MFMA.
// DT: 0 = fp16 MFMA, 1 = bf16 MFMA.
// EPI: 0 = qkv write (fp16 q/k cols <2048, bf16 v cols >=2048)
//      1 = exp -> bf16     2 = *aux[row] -> fp16     3 = +aux[col] -> fp32
template<int EPI, int DT>
__global__ __launch_bounds__(256, 4)
void gemm_tile(const short* __restrict__ A, int lda, long long bsA,
               const short* __restrict__ B, int ldb, long long bsB,
               void* __restrict__ Cv, int ldc, long long bsC,
               int K, const float* __restrict__ aux, long long bsAux) {
  __shared__ __align__(16) short As[128 * 72];   // pad 64 -> 72: 2-way conflicts (free)
  __shared__ __align__(16) short Bs[128 * 72];

  const int t = threadIdx.x;
  const int z = blockIdx.z;
  A += (size_t)z * bsA;
  B += (size_t)z * bsB;
  const float* auxp = aux + (size_t)z * bsAux;

  // T1: XCD-aware swizzle (grid x*y is a multiple of 8 for all launches).
  // Consecutive HW block ids (round-robin over XCDs) map to strided tile ids,
  // so each XCD owns a contiguous run of tiles sharing A-panels in its L2.
  const int nwg = gridDim.x * gridDim.y;
  const int lin = blockIdx.y * gridDim.x + blockIdx.x;
  const int swz = (lin & 7) * (nwg >> 3) + (lin >> 3);
  const int brow = (swz / gridDim.x) * 128;
  const int bcol = (swz % gridDim.x) * 128;

  // staging: thread t owns 64 contiguous bytes of row t/2 (two threads/row)
  const int srow = t >> 1;
  const int scol = (t & 1) << 5;
  const short* Ag = A + (size_t)(brow + srow) * lda + scol;
  const short* Bg = B + (size_t)(bcol + srow) * ldb + scol;
  short* Asw = &As[srow * 72 + scol];
  short* Bsw = &Bs[srow * 72 + scol];

  const int lane = t & 63;
  const int wid  = t >> 6;
  const int wr = (wid >> 1) * 64;      // wave row offset in tile
  const int wc = (wid & 1) * 64;       // wave col offset in tile
  const int fr = lane & 15;
  const int fg = lane >> 4;

  fx4 acc[4][4] = {};

  // T14 prefetch: regs hold tile t while LDS holds tile t-1's staging.
  s16x8 ar[4], br[4];
#pragma unroll
  for (int c = 0; c < 4; ++c) ar[c] = *reinterpret_cast<const s16x8*>(Ag + c * 8);
#pragma unroll
  for (int c = 0; c < 4; ++c) br[c] = *reinterpret_cast<const s16x8*>(Bg + c * 8);

  for (int kt = 0; kt < K; kt += 64) {
    __syncthreads();   // previous iter's LDS reads done
#pragma unroll
    for (int c = 0; c < 4; ++c) *reinterpret_cast<s16x8*>(Asw + c * 8) = ar[c];
#pragma unroll
    for (int c = 0; c < 4; ++c) *reinterpret_cast<s16x8*>(Bsw + c * 8) = br[c];
    __syncthreads();   // tile staged

    // issue next tile's global loads NOW; latency hides under compute below
    if (kt + 64 < K) {
#pragma unroll
      for (int c = 0; c < 4; ++c) ar[c] = *reinterpret_cast<const s16x8*>(Ag + kt + 64 + c * 8);
#pragma unroll
      for (int c = 0; c < 4; ++c) br[c] = *reinterpret_cast<const s16x8*>(Bg + kt + 64 + c * 8);
    }

#pragma unroll
    for (int kk = 0; kk < 64; kk += 32) {
      s16x8 af[4], bfv[4];
#pragma unroll
      for (int m = 0; m < 4; ++m)
        af[m] = *reinterpret_cast<const s16x8*>(&As[(wr + m * 16 + fr) * 72 + kk + fg * 8]);
#pragma unroll
      for (int n = 0; n < 4; ++n)
        bfv[n] = *reinterpret_cast<const s16x8*>(&Bs[(wc + n * 16 + fr) * 72 + kk + fg * 8]);
#pragma unroll
      for (int m = 0; m < 4; ++m)
#pragma unroll
        for (int n = 0; n < 4; ++n) {
          if constexpr (DT == 0)
            acc[m][n] = __builtin_amdgcn_mfma_f32_16x16x32_f16(
                __builtin_bit_cast(h16x8, af[m]), __builtin_bit_cast(h16x8, bfv[n]),
                acc[m][n], 0, 0, 0);
          else
            acc[m][n] = __builtin_amdgcn_mfma_f32_16x16x32_bf16(af[m], bfv[n], acc[m][n], 0, 0, 0);
        }
    }
  }

  // ---- epilogue: D row = (lane>>4)*4 + j, col = lane&15 (verified layout) ----
  const int row0 = brow + wr + fg * 4;
  const int col0 = bcol + wc + fr;
  if constexpr (EPI == 3) {
    float* Cf = reinterpret_cast<float*>(Cv) + (size_t)z * bsC;
#pragma unroll
    for (int m = 0; m < 4; ++m)
#pragma unroll
      for (int n = 0; n < 4; ++n) {
        const int col = col0 + n * 16;
        const float bo = auxp[col];
#pragma unroll
        for (int j = 0; j < 4; ++j)
          Cf[(size_t)(row0 + m * 16 + j) * ldc + col] = acc[m][n][j] + bo;
      }
  } else {
    short* Cb = reinterpret_cast<short*>(Cv) + (size_t)z * bsC;
    const bool isv = (bcol >= 2048);   // v-columns of the qkv GEMM -> bf16
#pragma unroll
    for (int m = 0; m < 4; ++m)
#pragma unroll
      for (int j = 0; j < 4; ++j) {
        const int row = row0 + m * 16 + j;
        float rs = 1.0f;
        if constexpr (EPI == 2) rs = auxp[row];
#pragma unroll
        for (int n = 0; n < 4; ++n) {
          float v = acc[m][n][j];
          short o;
          if constexpr (EPI == 0) o = isv ? f2bs(v) : f2hs(v);
          if constexpr (EPI == 1) o = f2bs(exp2f(v * 1.4426950408889634f));
          if constexpr (EPI == 2) o = f2hs(v * rs);
          Cb[(size_t)row * ldc + col0 + n * 16] = o;
        }
      }
  }
}

// ---------------- launch ----------------

extern "C" void kernel_launch(void* const* d_in, const int* in_sizes, int n_in,
                              void* d_out, int out_size, void* d_ws, size_t ws_size,
                              hipStream_t stream) {
  const float* x    = (const float*)d_in[0];   // [4,2048,1024]
  const float* Wqkv = (const float*)d_in[1];   // [1024,3072]
  const float* Wout = (const float*)d_in[2];   // [1024,1024]
  const float* bout = (const float*)d_in[3];   // [1024]
  float* out = (float*)d_out;                  // [4,2048,1024] fp32

  // workspace layout (bytes)
  char* ws = (char*)d_ws;
  short* qkv   = (short*)(ws + 0);             //  50331648  q/k fp16, v bf16 [8192][3072]
  short* WqkvT = (short*)(ws + 50331648);      //   6291456  fp16 [3072][1024]
  short* WoutT = (short*)(ws + 56623104);      //   2097152  fp16 [1024][1024]
  short* P     = (short*)(ws + 58720256);      //  33554432  bf16 [4][2048][2048]
  short* VT    = (short*)(ws + 92274688);      //  16777216  bf16 [4][1024][2048]
  short* xh    = (short*)(ws + 109051904);     //  16777216  fp16 x  (later reused as attn)
  float* invl  = (float*)(ws + 125829120);     //     32768
  if (ws_size < 125861888) return;             // insufficient scratch -> visible failure
  short* attn = xh;                            // x_fp16 dead after qkv GEMM

  cvt_f32_f16<<<8192, 256, 0, stream>>>(x, xh, 8388608 / 4);
  transpose_w<<<dim3(96, 32), 256, 0, stream>>>(Wqkv, 1024, 3072, WqkvT, 0.125f, 1024);
  transpose_w<<<dim3(32, 32), 256, 0, stream>>>(Wout, 1024, 1024, WoutT, 1.0f, 0);

  // qkv = x @ W_qkv                       (1536 blocks = 6/CU, balanced)
  gemm_tile<0, 0><<<dim3(24, 64, 1), 256, 0, stream>>>(
      xh, 1024, 0, WqkvT, 1024, 0, qkv, 3072, 0, 1024, bout /*unused*/, 0);
  // P = exp(q @ k^T)   (scale folded into Wq)   (1024 blocks = 4/CU)
  gemm_tile<1, 0><<<dim3(16, 16, 4), 256, 0, stream>>>(
      qkv, 3072, 2048LL * 3072, qkv + 1024, 3072, 2048LL * 3072,
      P, 2048, 2048LL * 2048, 1024, bout /*unused*/, 0);
  row_sums<<<2048, 256, 0, stream>>>(P, invl);
  transpose_v<<<dim3(32, 64, 4), 256, 0, stream>>>(qkv, VT);
  // attn = (P @ V) * invl                 (512 blocks = 2/CU)
  gemm_tile<2, 1><<<dim3(8, 16, 4), 256, 0, stream>>>(
      P, 2048, 2048LL * 2048, VT, 2048, 1024LL * 2048,
      attn, 1024, 2048LL * 1024, 2048, invl, 2048);
  // out = attn @ W_out + b                (512 blocks = 2/CU)
  gemm_tile<3, 0><<<dim3(8, 64, 1), 256, 0, stream>>>(
      attn, 1024, 0, WoutT, 1024, 0, out, 1024, 0, 1024, bout, 0);
}

// Round 6
// 217.993 us; speedup vs baseline: 1.2171x; 1.1710x over previous
//
#include <hip/hip_runtime.h>
#include <hip/hip_bf16.h>

// ---------------------------------------------------------------------------
// Attention_58248346469030:  out = softmax((x@Wq)(x@Wk)^T * sc) @ (x@Wv) @ Wout + b
// B=4, S=2048, DIM=1024, INNER=1024 (full-dim attention, no head split).
//
// Pipeline (fp16/bf16 MFMA, fp32 accumulate):
//   prep:  x -> fp16;  W_qkv -> fp16 transposed [n][k] (q pre-scaled by 0.125);
//          W_out -> fp16 transposed.
//   1) qkv  = x @ W_qkv       (q/k fp16 row-major; v bf16 written transposed->VT)
//   2) P    = exp(q @ k^T)    (fp16 MFMA, bf16 out; rowsum fused via shfl+atomicAdd)
//   3) attn = (P @ V) / rowsum  (bf16 MFMA, fp16 out)
//   4) out  = attn @ W_out + b  (fp16 MFMA, fp32 out)
//
// GEMM core: EXACT round-1 skeleton (best measured: qkv 71us, ~725 TF):
// 128x128 tile, BK=64, 4 waves (2x2), padded LDS stride 72 (2-way = free),
// reg-staged global->LDS, 2 barriers/K-tile. R4/R5's core changes reverted
// (measured -15us). This round: kernel-count fusion only (row_sums and
// transpose_v folded into GEMM epilogues).
// ---------------------------------------------------------------------------

typedef short    s16x8 __attribute__((ext_vector_type(8)));
typedef short    s16x4 __attribute__((ext_vector_type(4)));
typedef float    fx4   __attribute__((ext_vector_type(4)));
typedef _Float16 h16x8 __attribute__((ext_vector_type(8)));

__device__ __forceinline__ short f2bs(float f) {            // f32 -> bf16 bits (RNE)
  __hip_bfloat16 h = __float2bfloat16(f);
  short s; __builtin_memcpy(&s, &h, 2); return s;
}
__device__ __forceinline__ short f2hs(float f) {            // f32 -> fp16 bits (RNE)
  _Float16 h = (_Float16)f;
  short s; __builtin_memcpy(&s, &h, 2); return s;
}
__device__ __forceinline__ float b2f(short s) {             // bf16 bits -> f32
  unsigned u = ((unsigned)(unsigned short)s) << 16;
  float f; __builtin_memcpy(&f, &u, 4); return f;
}

// ---------------- prep kernels ----------------

__global__ void cvt_f32_f16(const float* __restrict__ in, short* __restrict__ out, int n4) {
  int i = blockIdx.x * blockDim.x + threadIdx.x;
  if (i < n4) {
    float4 v = reinterpret_cast<const float4*>(in)[i];
    s16x4 o;
    o.x = f2hs(v.x); o.y = f2hs(v.y); o.z = f2hs(v.z); o.w = f2hs(v.w);
    reinterpret_cast<s16x4*>(out)[i] = o;
  }
}

// WT[n][k] = W[k][n] * (n < scaleN ? qscale : 1), fp16 out.
__global__ void transpose_w(const float* __restrict__ W, int K, int N,
                            short* __restrict__ WT, float qscale, int scaleN) {
  __shared__ float tile[32][33];
  int k0 = blockIdx.y * 32, n0 = blockIdx.x * 32;
  int r = threadIdx.x >> 5, c = threadIdx.x & 31;
  for (int rr = r; rr < 32; rr += 8)
    tile[rr][c] = W[(size_t)(k0 + rr) * N + n0 + c];
  __syncthreads();
  for (int rr = r; rr < 32; rr += 8) {
    int n = n0 + rr;
    float s = (n < scaleN) ? qscale : 1.0f;
    WT[(size_t)n * K + k0 + c] = f2hs(tile[c][rr] * s);
  }
}

// ---------------- shared GEMM skeleton (exact R1 core) ----------------
// C[M][N] = A[M][K] @ B'[N][K]^T  (both operands 16-bit, k-contiguous rows)
// 128x128 tile, BK=64, 4 waves (2x2), each wave 64x64 = 4x4 16x16x32 MFMA.
// DT: 0 = fp16 MFMA, 1 = bf16 MFMA.
// EPI: 0 = qkv write (fp16 q/k cols <2048 -> Cv; v cols >=2048 -> bf16 VT=Cv2)
//      1 = exp -> bf16 + fused rowsum (shfl-reduce + atomicAdd into auxw)
//      2 = /aux[row] -> fp16     3 = +aux[col] -> fp32
template<int EPI, int DT>
__global__ __launch_bounds__(256, 2)
void gemm_tile(const short* __restrict__ A, int lda, long long bsA,
               const short* __restrict__ B, int ldb, long long bsB,
               void* __restrict__ Cv, int ldc, long long bsC,
               int K, const float* __restrict__ aux, long long bsAux,
               short* __restrict__ Cv2, float* __restrict__ auxw) {
  __shared__ __align__(16) short As[128 * 72];   // pad 64 -> 72: 2-way conflicts (free)
  __shared__ __align__(16) short Bs[128 * 72];

  const int t = threadIdx.x;
  const int z = blockIdx.z;
  A += (size_t)z * bsA;
  B += (size_t)z * bsB;

  const int brow = blockIdx.y * 128;
  const int bcol = blockIdx.x * 128;

  // staging: thread t owns 64 contiguous bytes (32 elems) of row t/2
  const int srow = t >> 1;
  const int scol = (t & 1) << 5;
  const short* Ag = A + (size_t)(brow + srow) * lda + scol;
  const short* Bg = B + (size_t)(bcol + srow) * ldb + scol;
  short* Asw = &As[srow * 72 + scol];
  short* Bsw = &Bs[srow * 72 + scol];

  const int lane = t & 63;
  const int wid  = t >> 6;
  const int wr = (wid >> 1) * 64;      // wave row offset in tile
  const int wc = (wid & 1) * 64;       // wave col offset in tile
  const int fr = lane & 15;
  const int fg = lane >> 4;

  fx4 acc[4][4] = {};

  for (int kt = 0; kt < K; kt += 64) {
    s16x8 ar[4], br[4];
#pragma unroll
    for (int c = 0; c < 4; ++c) ar[c] = *reinterpret_cast<const s16x8*>(Ag + kt + c * 8);
#pragma unroll
    for (int c = 0; c < 4; ++c) br[c] = *reinterpret_cast<const s16x8*>(Bg + kt + c * 8);
    __syncthreads();   // previous iter's LDS reads done
#pragma unroll
    for (int c = 0; c < 4; ++c) *reinterpret_cast<s16x8*>(Asw + c * 8) = ar[c];
#pragma unroll
    for (int c = 0; c < 4; ++c) *reinterpret_cast<s16x8*>(Bsw + c * 8) = br[c];
    __syncthreads();   // tile staged

#pragma unroll
    for (int kk = 0; kk < 64; kk += 32) {
      s16x8 af[4], bfv[4];
#pragma unroll
      for (int m = 0; m < 4; ++m)
        af[m] = *reinterpret_cast<const s16x8*>(&As[(wr + m * 16 + fr) * 72 + kk + fg * 8]);
#pragma unroll
      for (int n = 0; n < 4; ++n)
        bfv[n] = *reinterpret_cast<const s16x8*>(&Bs[(wc + n * 16 + fr) * 72 + kk + fg * 8]);
#pragma unroll
      for (int m = 0; m < 4; ++m)
#pragma unroll
        for (int n = 0; n < 4; ++n) {
          if constexpr (DT == 0)
            acc[m][n] = __builtin_amdgcn_mfma_f32_16x16x32_f16(
                __builtin_bit_cast(h16x8, af[m]), __builtin_bit_cast(h16x8, bfv[n]),
                acc[m][n], 0, 0, 0);
          else
            acc[m][n] = __builtin_amdgcn_mfma_f32_16x16x32_bf16(af[m], bfv[n], acc[m][n], 0, 0, 0);
        }
    }
  }

  // ---- epilogue: D row = (lane>>4)*4 + j, col = lane&15 (verified layout) ----
  const int row0 = brow + wr + fg * 4;
  const int col0 = bcol + wc + fr;
  const float* auxp = aux + (size_t)z * bsAux;

  if constexpr (EPI == 3) {
    float* Cf = reinterpret_cast<float*>(Cv) + (size_t)z * bsC;
#pragma unroll
    for (int m = 0; m < 4; ++m)
#pragma unroll
      for (int n = 0; n < 4; ++n) {
        const int col = col0 + n * 16;
        const float bo = auxp[col];
#pragma unroll
        for (int j = 0; j < 4; ++j)
          Cf[(size_t)(row0 + m * 16 + j) * ldc + col] = acc[m][n][j] + bo;
      }
  } else if constexpr (EPI == 0) {
    short* Cb = reinterpret_cast<short*>(Cv);
    if (bcol < 2048) {                    // q/k columns -> fp16, row-major
#pragma unroll
      for (int m = 0; m < 4; ++m)
#pragma unroll
        for (int j = 0; j < 4; ++j) {
          const int row = row0 + m * 16 + j;
#pragma unroll
          for (int n = 0; n < 4; ++n)
            Cb[(size_t)row * ldc + col0 + n * 16] = f2hs(acc[m][n][j]);
        }
    } else {                              // v columns -> bf16 into VT[b][d][t]
#pragma unroll
      for (int m = 0; m < 4; ++m)
#pragma unroll
        for (int j = 0; j < 4; ++j) {
          const int row = row0 + m * 16 + j;
          const int zb = row >> 11, s = row & 2047;
#pragma unroll
          for (int n = 0; n < 4; ++n) {
            const int d = col0 + n * 16 - 2048;
            Cv2[((size_t)(zb << 10) + d) * 2048 + s] = f2bs(acc[m][n][j]);
          }
        }
    }
  } else if constexpr (EPI == 1) {
    // P = exp(dots), bf16 out; fused row-sum: per row, 4 vals/lane over the
    // 16-lane fr-group (64 cols/wave), shfl-xor reduce, 1 atomicAdd per wave.
    short* Cb = reinterpret_cast<short*>(Cv) + (size_t)z * bsC;
    float* rs_out = auxw + (size_t)z * bsAux;
#pragma unroll
    for (int m = 0; m < 4; ++m)
#pragma unroll
      for (int j = 0; j < 4; ++j) {
        const int row = row0 + m * 16 + j;
        float e[4];
#pragma unroll
        for (int n = 0; n < 4; ++n) {
          e[n] = exp2f(acc[m][n][j] * 1.4426950408889634f);
          Cb[(size_t)row * ldc + col0 + n * 16] = f2bs(e[n]);
        }
        float ps = (e[0] + e[1]) + (e[2] + e[3]);
        ps += __shfl_xor(ps, 1);
        ps += __shfl_xor(ps, 2);
        ps += __shfl_xor(ps, 4);
        ps += __shfl_xor(ps, 8);
        if (fr == 0) atomicAdd(&rs_out[row], ps);
      }
  } else {                                // EPI == 2: attn = acc / rowsum
    short* Cb = reinterpret_cast<short*>(Cv) + (size_t)z * bsC;
#pragma unroll
    for (int m = 0; m < 4; ++m)
#pragma unroll
      for (int j = 0; j < 4; ++j) {
        const int row = row0 + m * 16 + j;
        const float rs = 1.0f / auxp[row];
#pragma unroll
        for (int n = 0; n < 4; ++n)
          Cb[(size_t)row * ldc + col0 + n * 16] = f2hs(acc[m][n][j] * rs);
      }
  }
}

// ---------------- launch ----------------

extern "C" void kernel_launch(void* const* d_in, const int* in_sizes, int n_in,
                              void* d_out, int out_size, void* d_ws, size_t ws_size,
                              hipStream_t stream) {
  const float* x    = (const float*)d_in[0];   // [4,2048,1024]
  const float* Wqkv = (const float*)d_in[1];   // [1024,3072]
  const float* Wout = (const float*)d_in[2];   // [1024,1024]
  const float* bout = (const float*)d_in[3];   // [1024]
  float* out = (float*)d_out;                  // [4,2048,1024] fp32

  // workspace layout (bytes)
  char* ws = (char*)d_ws;
  short* qkv   = (short*)(ws + 0);             //  50331648  q/k fp16 [8192][3072]
  short* WqkvT = (short*)(ws + 50331648);      //   6291456  fp16 [3072][1024]
  short* WoutT = (short*)(ws + 56623104);      //   2097152  fp16 [1024][1024]
  short* P     = (short*)(ws + 58720256);      //  33554432  bf16 [4][2048][2048]
  short* VT    = (short*)(ws + 92274688);      //  16777216  bf16 [4][1024][2048]
  short* xh    = (short*)(ws + 109051904);     //  16777216  fp16 x (reused as attn)
  float* rsum  = (float*)(ws + 125829120);     //     32768  [4][2048] row sums
  if (ws_size < 125861888) return;             // insufficient scratch -> visible failure
  short* attn = xh;                            // x_fp16 dead after qkv GEMM

  hipMemsetAsync(rsum, 0, 8192 * sizeof(float), stream);
  cvt_f32_f16<<<8192, 256, 0, stream>>>(x, xh, 8388608 / 4);
  transpose_w<<<dim3(96, 32), 256, 0, stream>>>(Wqkv, 1024, 3072, WqkvT, 0.125f, 1024);
  transpose_w<<<dim3(32, 32), 256, 0, stream>>>(Wout, 1024, 1024, WoutT, 1.0f, 0);

  // qkv = x @ W_qkv   (q/k -> qkv buf; v -> VT transposed)
  gemm_tile<0, 0><<<dim3(24, 64, 1), 256, 0, stream>>>(
      xh, 1024, 0, WqkvT, 1024, 0, qkv, 3072, 0, 1024, bout, 0, VT, nullptr);
  // P = exp(q @ k^T) + fused rowsum   (scale folded into Wq)
  gemm_tile<1, 0><<<dim3(16, 16, 4), 256, 0, stream>>>(
      qkv, 3072, 2048LL * 3072, qkv + 1024, 3072, 2048LL * 3072,
      P, 2048, 2048LL * 2048, 1024, bout, 2048, nullptr, rsum);
  // attn = (P @ V) / rowsum
  gemm_tile<2, 1><<<dim3(8, 16, 4), 256, 0, stream>>>(
      P, 2048, 2048LL * 2048, VT, 2048, 1024LL * 2048,
      attn, 1024, 2048LL * 1024, 2048, rsum, 2048, nullptr, nullptr);
  // out = attn @ W_out + b
  gemm_tile<3, 0><<<dim3(8, 64, 1), 256, 0, stream>>>(
      attn, 1024, 0, WoutT, 1024, 0, out, 1024, 0, 1024, bout, 0, nullptr, nullptr);
}